// Round 5
// baseline (371.168 us; speedup 1.0000x reference)
//
#include <hip/hip_runtime.h>
#include <hip/hip_bf16.h>
#include <cstdint>
#include <cstddef>

// Problem constants
#define B_  4
#define S_  4096
#define A_  512
#define H_  1024
#define NH_ 16
#define HD_ 64

typedef __bf16 bf16;
typedef __bf16 bf16x8 __attribute__((ext_vector_type(8)));
typedef __bf16 bf16x4 __attribute__((ext_vector_type(4)));
typedef float  fx4    __attribute__((ext_vector_type(4)));

__device__ __forceinline__ bf16x8 cvt8(float4 a, float4 b) {
    bf16x8 o;
    o[0] = (bf16)a.x; o[1] = (bf16)a.y; o[2] = (bf16)a.z; o[3] = (bf16)a.w;
    o[4] = (bf16)b.x; o[5] = (bf16)b.y; o[6] = (bf16)b.z; o[7] = (bf16)b.w;
    return o;
}

// ---------------------------------------------------------------- fused QKV GEMM (fp32 in, one dispatch, 1280 blocks)
// Inputs are raw fp32 (hs/at/W*); conversion to bf16 happens in-register
// during staging. All-VGPR staging: no global_load_lds => the staging
// barrier drains lgkm only, and next-tile fp32 loads stay in flight across
// the entire MFMA phase (fine-grained pipeline the m97 structure can't do).
// id <1024: Q = hs@wq^T (+bq) * log2e/8 -> Qb bf16
// id <1152: K = at@wk^T (+bk)           -> Kb bf16
// else    : V = at@wv^T (+bv)           -> Vtb bf16 transposed [(b*H+n)*512+a]
__global__ __launch_bounds__(256) void qkv_gemm(const float* __restrict__ hs,
                                                const float* __restrict__ at,
                                                const float* __restrict__ wq,
                                                const float* __restrict__ wk,
                                                const float* __restrict__ wv,
                                                const float* __restrict__ bq,
                                                const float* __restrict__ bk,
                                                const float* __restrict__ bv,
                                                bf16* __restrict__ Qb,
                                                bf16* __restrict__ Kb,
                                                bf16* __restrict__ Vtb) {
    __shared__ __align__(16) bf16 As[128 * 32];
    __shared__ __align__(16) bf16 Bs[128 * 32];

    const int id = blockIdx.x;
    int mode, m0, n0;
    const float *A, *Bt, *bias;
    if (id < 1024)      { mode = 0; m0 = (id & 127) * 128; n0 = (id >> 7) * 128; A = hs; Bt = wq; bias = bq; }
    else if (id < 1152) { int t = id - 1024; mode = 1; m0 = (t & 15) * 128; n0 = (t >> 4) * 128; A = at; Bt = wk; bias = bk; }
    else                { int t = id - 1152; mode = 2; m0 = (t & 15) * 128; n0 = (t >> 4) * 128; A = at; Bt = wv; bias = bv; }

    const int tid  = threadIdx.x;
    const int lane = tid & 63;
    const int wv_  = tid >> 6;
    const int wr   = wv_ >> 1, wc = wv_ & 1;
    const int lr   = lane & 15, kq = lane >> 4;

    fx4 acc[4][4] = {};

    const float* Ag = A  + (size_t)m0 * 1024;
    const float* Bg = Bt + (size_t)n0 * 1024;
    const int c0 = tid, c1 = tid + 256;
    const int row0 = c0 >> 2, kc0 = (c0 & 3) * 8;
    const int row1 = c1 >> 2, kc1 = (c1 & 3) * 8;

    // prefetch tile 0 (fp32)
    float4 pa0 = *(const float4*)(Ag + (size_t)row0 * 1024 + kc0);
    float4 pa1 = *(const float4*)(Ag + (size_t)row0 * 1024 + kc0 + 4);
    float4 pa2 = *(const float4*)(Ag + (size_t)row1 * 1024 + kc1);
    float4 pa3 = *(const float4*)(Ag + (size_t)row1 * 1024 + kc1 + 4);
    float4 pb0 = *(const float4*)(Bg + (size_t)row0 * 1024 + kc0);
    float4 pb1 = *(const float4*)(Bg + (size_t)row0 * 1024 + kc0 + 4);
    float4 pb2 = *(const float4*)(Bg + (size_t)row1 * 1024 + kc1);
    float4 pb3 = *(const float4*)(Bg + (size_t)row1 * 1024 + kc1 + 4);

    for (int k0 = 0; k0 < 1024; k0 += 32) {
        __syncthreads();  // prev MFMA done reading LDS
        *(bf16x8*)&As[c0 * 8] = cvt8(pa0, pa1);
        *(bf16x8*)&As[c1 * 8] = cvt8(pa2, pa3);
        *(bf16x8*)&Bs[c0 * 8] = cvt8(pb0, pb1);
        *(bf16x8*)&Bs[c1 * 8] = cvt8(pb2, pb3);
        __syncthreads();  // lgkm-only drain (no vmem->LDS in flight)

        if (k0 + 32 < 1024) {  // next-tile loads: in flight across the MFMA phase
            int kn = k0 + 32;
            pa0 = *(const float4*)(Ag + (size_t)row0 * 1024 + kn + kc0);
            pa1 = *(const float4*)(Ag + (size_t)row0 * 1024 + kn + kc0 + 4);
            pa2 = *(const float4*)(Ag + (size_t)row1 * 1024 + kn + kc1);
            pa3 = *(const float4*)(Ag + (size_t)row1 * 1024 + kn + kc1 + 4);
            pb0 = *(const float4*)(Bg + (size_t)row0 * 1024 + kn + kc0);
            pb1 = *(const float4*)(Bg + (size_t)row0 * 1024 + kn + kc0 + 4);
            pb2 = *(const float4*)(Bg + (size_t)row1 * 1024 + kn + kc1);
            pb3 = *(const float4*)(Bg + (size_t)row1 * 1024 + kn + kc1 + 4);
        }

        bf16x8 af[4], bfr[4];
#pragma unroll
        for (int i = 0; i < 4; i++) af[i]  = *(const bf16x8*)&As[(wr * 64 + i * 16 + lr) * 32 + kq * 8];
#pragma unroll
        for (int j = 0; j < 4; j++) bfr[j] = *(const bf16x8*)&Bs[(wc * 64 + j * 16 + lr) * 32 + kq * 8];
#pragma unroll
        for (int i = 0; i < 4; i++)
#pragma unroll
            for (int j = 0; j < 4; j++)
                acc[i][j] = __builtin_amdgcn_mfma_f32_16x16x32_bf16(af[i], bfr[j], acc[i][j], 0, 0, 0);
    }

    float bb[4];
#pragma unroll
    for (int j = 0; j < 4; j++) bb[j] = bias[n0 + wc * 64 + j * 16 + lr];

    if (mode == 0) {
        const float sc = 0.18033688011112042f;  // log2(e)/8 prescale for exp2-domain scores
#pragma unroll
        for (int i = 0; i < 4; i++) {
            int row = m0 + wr * 64 + i * 16 + kq * 4;
#pragma unroll
            for (int j = 0; j < 4; j++) {
                int col = n0 + wc * 64 + j * 16 + lr;
#pragma unroll
                for (int r = 0; r < 4; r++)
                    Qb[(size_t)(row + r) * 1024 + col] = (bf16)((acc[i][j][r] + bb[j]) * sc);
            }
        }
    } else if (mode == 1) {
#pragma unroll
        for (int i = 0; i < 4; i++) {
            int row = m0 + wr * 64 + i * 16 + kq * 4;
#pragma unroll
            for (int j = 0; j < 4; j++) {
                int col = n0 + wc * 64 + j * 16 + lr;
#pragma unroll
                for (int r = 0; r < 4; r++)
                    Kb[(size_t)(row + r) * 1024 + col] = (bf16)(acc[i][j][r] + bb[j]);
            }
        }
    } else {
        // V: transposed output, r-contiguous -> packed bf16x4 stores
#pragma unroll
        for (int i = 0; i < 4; i++) {
            int m = m0 + wr * 64 + i * 16 + kq * 4;  // m = b*512 + a
            int bidx = m >> 9, a = m & 511;
#pragma unroll
            for (int j = 0; j < 4; j++) {
                int col = n0 + wc * 64 + j * 16 + lr;
                bf16x4 o;
#pragma unroll
                for (int r = 0; r < 4; r++) o[r] = (bf16)(acc[i][j][r] + bb[j]);
                *(bf16x4*)&Vtb[((size_t)bidx * H_ + col) * A_ + a] = o;
            }
        }
    }
}

// ---------------------------------------------------------------- O-proj GEMM: delta bf16 = (ctx@Wo^T + bo) * rs
// A = ctx bf16, B = Wo fp32 (converted in staging). Same all-VGPR pipeline.
__global__ __launch_bounds__(256) void gemm_o(const bf16* __restrict__ A,
                                              const float* __restrict__ Bt,
                                              const float* __restrict__ bias,
                                              bf16* __restrict__ C,
                                              const float* __restrict__ rsp) {
    __shared__ __align__(16) bf16 As[128 * 32];
    __shared__ __align__(16) bf16 Bs[128 * 32];

    const int tid  = threadIdx.x;
    const int lane = tid & 63;
    const int wv_  = tid >> 6;
    const int wr   = wv_ >> 1, wc = wv_ & 1;
    const int lr   = lane & 15, kq = lane >> 4;
    const int m0   = blockIdx.x * 128, n0 = blockIdx.y * 128;

    fx4 acc[4][4] = {};

    const bf16*  Ag = A  + (size_t)m0 * 1024;
    const float* Bg = Bt + (size_t)n0 * 1024;
    const int c0 = tid, c1 = tid + 256;
    const int row0 = c0 >> 2, kc0 = (c0 & 3) * 8;
    const int row1 = c1 >> 2, kc1 = (c1 & 3) * 8;

    bf16x8 qa0 = *(const bf16x8*)(Ag + (size_t)row0 * 1024 + kc0);
    bf16x8 qa1 = *(const bf16x8*)(Ag + (size_t)row1 * 1024 + kc1);
    float4 pb0 = *(const float4*)(Bg + (size_t)row0 * 1024 + kc0);
    float4 pb1 = *(const float4*)(Bg + (size_t)row0 * 1024 + kc0 + 4);
    float4 pb2 = *(const float4*)(Bg + (size_t)row1 * 1024 + kc1);
    float4 pb3 = *(const float4*)(Bg + (size_t)row1 * 1024 + kc1 + 4);

    for (int k0 = 0; k0 < 1024; k0 += 32) {
        __syncthreads();
        *(bf16x8*)&As[c0 * 8] = qa0;
        *(bf16x8*)&As[c1 * 8] = qa1;
        *(bf16x8*)&Bs[c0 * 8] = cvt8(pb0, pb1);
        *(bf16x8*)&Bs[c1 * 8] = cvt8(pb2, pb3);
        __syncthreads();

        if (k0 + 32 < 1024) {
            int kn = k0 + 32;
            qa0 = *(const bf16x8*)(Ag + (size_t)row0 * 1024 + kn + kc0);
            qa1 = *(const bf16x8*)(Ag + (size_t)row1 * 1024 + kn + kc1);
            pb0 = *(const float4*)(Bg + (size_t)row0 * 1024 + kn + kc0);
            pb1 = *(const float4*)(Bg + (size_t)row0 * 1024 + kn + kc0 + 4);
            pb2 = *(const float4*)(Bg + (size_t)row1 * 1024 + kn + kc1);
            pb3 = *(const float4*)(Bg + (size_t)row1 * 1024 + kn + kc1 + 4);
        }

        bf16x8 af[4], bfr[4];
#pragma unroll
        for (int i = 0; i < 4; i++) af[i]  = *(const bf16x8*)&As[(wr * 64 + i * 16 + lr) * 32 + kq * 8];
#pragma unroll
        for (int j = 0; j < 4; j++) bfr[j] = *(const bf16x8*)&Bs[(wc * 64 + j * 16 + lr) * 32 + kq * 8];
#pragma unroll
        for (int i = 0; i < 4; i++)
#pragma unroll
            for (int j = 0; j < 4; j++)
                acc[i][j] = __builtin_amdgcn_mfma_f32_16x16x32_bf16(af[i], bfr[j], acc[i][j], 0, 0, 0);
    }

    float bb[4];
#pragma unroll
    for (int j = 0; j < 4; j++) bb[j] = bias[n0 + wc * 64 + j * 16 + lr];
    float rs = fminf(fmaxf(rsp[0], 0.f), 0.3f);
#pragma unroll
    for (int i = 0; i < 4; i++) {
        int row = m0 + wr * 64 + i * 16 + kq * 4;
#pragma unroll
        for (int j = 0; j < 4; j++) {
            int col = n0 + wc * 64 + j * 16 + lr;
#pragma unroll
            for (int r = 0; r < 4; r++)
                C[(size_t)(row + r) * 1024 + col] = (bf16)(rs * (acc[i][j][r] + bb[j]));
        }
    }
}

// ---------------------------------------------------------------- attention v4 (unchanged from R4)
// Permuted V^T LDS layout: within each 32-a-block, position
// p = 32ks + 8kq + 4hi + j holds a = 32ks + 16hi + 4kq + j, so each PV
// B-fragment is ONE aligned b128 read (conflict-free stride-36-word form).
__global__ __launch_bounds__(256, 4) void attn_kernel(const bf16* __restrict__ Q,
                                                      const bf16* __restrict__ Kb,
                                                      const bf16* __restrict__ Vt,
                                                      const int* __restrict__ mask,
                                                      bf16* __restrict__ ctx) {
    __shared__ __align__(16) bf16 Qs[128 * 72];   // padded; reused for ctx staging
    __shared__ __align__(16) bf16 Ks[64 * 72];    // K [a][d], padded
    __shared__ __align__(16) bf16 Vts[64 * 72];   // V^T [d][a-permuted], padded
    __shared__ float smask[512];                  // caps: +/- 50*log2e
    __shared__ float dnm[128];

    const int tid  = threadIdx.x;
    const int lane = tid & 63;
    const int wv   = tid >> 6;
    const int lr   = lane & 15, kq = lane >> 4;
    const int st = blockIdx.x, h = blockIdx.y, b = blockIdx.z;
    const int m0 = b * S_ + st * 128;
    const float LO = -72.134752f;                 // -50*log2e

    // --- stage Q (padded, via VGPRs) + mask caps
    bf16x8 qtmp[4];
#pragma unroll
    for (int i = 0; i < 4; i++) {
        int c = tid + i * 256, row = c >> 3, ch = c & 7;
        qtmp[i] = *(const bf16x8*)(Q + (size_t)(m0 + row) * H_ + h * 64 + ch * 8);
    }
    smask[tid]       = (mask[b * A_ + tid] > 0)       ? -LO : LO;
    smask[tid + 256] = (mask[b * A_ + tid + 256] > 0) ? -LO : LO;
#pragma unroll
    for (int i = 0; i < 4; i++) {
        int c = tid + i * 256, row = c >> 3, ch = c & 7;
        *(bf16x8*)&Qs[row * 72 + ch * 8] = qtmp[i];
    }

    // staging coords
    const int srow = tid >> 2, sseg = tid & 3;
    const size_t kg = (size_t)(b * A_ + srow) * H_ + h * 64 + sseg * 16;
    const bf16* vrow = Vt + (size_t)(b * H_ + h * 64 + srow) * A_;
    const int va0 = 32 * (sseg >> 1) + 4 * ((2 * sseg) & 3);      // u=0 source base
    const int va1 = 32 * (sseg >> 1) + 4 * ((2 * sseg + 1) & 3);  // u=1 source base

    // prefetch tile 0
    bf16x8 kr0 = *(const bf16x8*)(Kb + kg);
    bf16x8 kr1 = *(const bf16x8*)(Kb + kg + 8);
    bf16x4 v00 = *(const bf16x4*)(vrow + va0);
    bf16x4 v01 = *(const bf16x4*)(vrow + va0 + 16);
    bf16x4 v10 = *(const bf16x4*)(vrow + va1);
    bf16x4 v11 = *(const bf16x4*)(vrow + va1 + 16);

    fx4 acco[2][4] = {};          // [st][dt] : ctx[s=wv*32+st*16+kq*4+r][d=dt*16+lr]
    float dloc[2] = {0.f, 0.f};   // per-lane partial denominators per s-16-block

    for (int it = 0; it < 8; it++) {
        const int a0 = it * 64;
        __syncthreads();  // prev compute done reading Ks/Vts (it=0: Q/mask writes ordered)
        *(bf16x8*)&Ks[srow * 72 + sseg * 16]      = kr0;
        *(bf16x8*)&Ks[srow * 72 + sseg * 16 + 8]  = kr1;
        *(bf16x8*)&Vts[srow * 72 + sseg * 16] =
            __builtin_shufflevector(v00, v01, 0, 1, 2, 3, 4, 5, 6, 7);
        *(bf16x8*)&Vts[srow * 72 + sseg * 16 + 8] =
            __builtin_shufflevector(v10, v11, 0, 1, 2, 3, 4, 5, 6, 7);
        __syncthreads();  // staging visible (lgkm only — no LDS-writing vmem in flight)

        if (it < 7) {     // register prefetch for it+1 (uniform branch)
            const size_t ko = kg + (size_t)(a0 + 64) * H_;
            kr0 = *(const bf16x8*)(Kb + ko);
            kr1 = *(const bf16x8*)(Kb + ko + 8);
            v00 = *(const bf16x4*)(vrow + a0 + 64 + va0);
            v01 = *(const bf16x4*)(vrow + a0 + 64 + va0 + 16);
            v10 = *(const bf16x4*)(vrow + a0 + 64 + va1);
            v11 = *(const bf16x4*)(vrow + a0 + 64 + va1 + 16);
        }

        // ---- S^T = K·Q^T  (M=a 64, N=s; wave owns s in [wv*32, wv*32+32))
        fx4 accs[4][2] = {};   // [mt][nt] : S^T[a=mt*16+kq*4+r][s=wv*32+nt*16+lr]
#pragma unroll
        for (int kk = 0; kk < 64; kk += 32) {
            bf16x8 kf[4], qf[2];
#pragma unroll
            for (int mt = 0; mt < 4; mt++)
                kf[mt] = *(const bf16x8*)&Ks[(mt * 16 + lr) * 72 + kk + kq * 8];
#pragma unroll
            for (int nt = 0; nt < 2; nt++)
                qf[nt] = *(const bf16x8*)&Qs[(wv * 32 + nt * 16 + lr) * 72 + kk + kq * 8];
#pragma unroll
            for (int mt = 0; mt < 4; mt++)
#pragma unroll
                for (int nt = 0; nt < 2; nt++)
                    accs[mt][nt] = __builtin_amdgcn_mfma_f32_16x16x32_bf16(kf[mt], qf[nt], accs[mt][nt], 0, 0, 0);
        }

        // ---- softmax numerator in-register: P fragments (bf16) + denom partials
        bf16x4 pf[4][2];
#pragma unroll
        for (int mt = 0; mt < 4; mt++) {
            fx4 cap = *(const fx4*)&smask[a0 + mt * 16 + kq * 4];
#pragma unroll
            for (int nt = 0; nt < 2; nt++) {
#pragma unroll
                for (int r = 0; r < 4; r++) {
                    float s2 = fmaxf(fminf(accs[mt][nt][r], cap[r]), LO);
                    float p  = __builtin_amdgcn_exp2f(s2);
                    pf[mt][nt][r] = (bf16)p;
                    dloc[nt] += p;
                }
            }
        }

        // ---- PV: ctx += P·V. A = P from regs (permuted k-order), B = V^T LDS (b128).
#pragma unroll
        for (int ks = 0; ks < 2; ks++) {
            bf16x8 pa[2];
#pragma unroll
            for (int stl = 0; stl < 2; stl++)
                pa[stl] = __builtin_shufflevector(pf[2 * ks][stl], pf[2 * ks + 1][stl],
                                                  0, 1, 2, 3, 4, 5, 6, 7);
#pragma unroll
            for (int dt = 0; dt < 4; dt++) {
                bf16x8 vf = *(const bf16x8*)&Vts[(dt * 16 + lr) * 72 + ks * 32 + kq * 8];
#pragma unroll
                for (int stl = 0; stl < 2; stl++)
                    acco[stl][dt] = __builtin_amdgcn_mfma_f32_16x16x32_bf16(pa[stl], vf, acco[stl][dt], 0, 0, 0);
            }
        }
    }

    // ---- denominators: reduce across quads, publish per s-row
#pragma unroll
    for (int nt = 0; nt < 2; nt++) {
        dloc[nt] += __shfl_xor(dloc[nt], 16);
        dloc[nt] += __shfl_xor(dloc[nt], 32);
    }
    if (kq == 0) {
        dnm[wv * 32 + lr]      = dloc[0];
        dnm[wv * 32 + 16 + lr] = dloc[1];
    }
    __syncthreads();  // dnm visible; Qs free (last read in final QK^T)

    // ---- normalize + stage ctx tile into Qs (padded), then vectorized store
#pragma unroll
    for (int stl = 0; stl < 2; stl++) {
        fx4 dv = *(const fx4*)&dnm[wv * 32 + stl * 16 + kq * 4];
        float ri[4];
#pragma unroll
        for (int r = 0; r < 4; r++) ri[r] = __builtin_amdgcn_rcpf(dv[r]);
#pragma unroll
        for (int dt = 0; dt < 4; dt++)
#pragma unroll
            for (int r = 0; r < 4; r++)
                Qs[(wv * 32 + stl * 16 + kq * 4 + r) * 72 + dt * 16 + lr] =
                    (bf16)(acco[stl][dt][r] * ri[r]);
    }
    __syncthreads();
#pragma unroll
    for (int i = 0; i < 4; i++) {
        int c = tid + i * 256, row = c >> 3, ch = c & 7;
        *(bf16x8*)&ctx[(size_t)(m0 + row) * H_ + h * 64 + ch * 8] = *(const bf16x8*)&Qs[row * 72 + ch * 8];
    }
}

// ---------------------------------------------------------------- LayerNorm: bf16 delta -> fp32 out
__global__ __launch_bounds__(256) void ln_kernel(const bf16* __restrict__ in,
                                                 float* __restrict__ out,
                                                 const float* __restrict__ gamma,
                                                 const float* __restrict__ beta) {
    __shared__ float red[8];
    const int tid = threadIdx.x;
    bf16x4 xb = *(const bf16x4*)&in[(size_t)blockIdx.x * 1024 + tid * 4];
    float x0 = (float)xb[0], x1 = (float)xb[1], x2 = (float)xb[2], x3 = (float)xb[3];
    float s = x0 + x1 + x2 + x3;
    float q = x0 * x0 + x1 * x1 + x2 * x2 + x3 * x3;
#pragma unroll
    for (int off = 32; off > 0; off >>= 1) {
        s += __shfl_down(s, off);
        q += __shfl_down(q, off);
    }
    if ((tid & 63) == 0) { red[(tid >> 6) * 2] = s; red[(tid >> 6) * 2 + 1] = q; }
    __syncthreads();
    s = red[0] + red[2] + red[4] + red[6];
    q = red[1] + red[3] + red[5] + red[7];
    float mean = s * (1.f / 1024.f);
    float var  = q * (1.f / 1024.f) - mean * mean;
    float inv  = rsqrtf(var + 1e-5f);
    float4 g  = ((const float4*)gamma)[tid];
    float4 bb = ((const float4*)beta)[tid];
    float4 y;
    y.x = (x0 - mean) * inv * g.x + bb.x;
    y.y = (x1 - mean) * inv * g.y + bb.y;
    y.z = (x2 - mean) * inv * g.z + bb.z;
    y.w = (x3 - mean) * inv * g.w + bb.w;
    ((float4*)(out + (size_t)blockIdx.x * 1024))[tid] = y;
}

// ---------------------------------------------------------------- launch
extern "C" void kernel_launch(void* const* d_in, const int* in_sizes, int n_in,
                              void* d_out, int out_size, void* d_ws, size_t ws_size,
                              hipStream_t stream) {
    const float* hs    = (const float*)d_in[0];
    const float* at    = (const float*)d_in[1];
    const int*   maskp = (const int*)d_in[2];
    const float* Wq    = (const float*)d_in[3];
    const float* bq    = (const float*)d_in[4];
    const float* Wk    = (const float*)d_in[5];
    const float* bk    = (const float*)d_in[6];
    const float* Wv    = (const float*)d_in[7];
    const float* bv    = (const float*)d_in[8];
    const float* Wo    = (const float*)d_in[9];
    const float* bo    = (const float*)d_in[10];
    const float* gamma = (const float*)d_in[11];
    const float* beta  = (const float*)d_in[12];
    const float* rsp   = (const float*)d_in[13];

    char* ws = (char*)d_ws;
    bf16* ctx = (bf16*)(ws + 0);          // 32 MB  [16384,1024]
    bf16* Qb  = (bf16*)(ws + 46137344);   // 32 MB  [16384,1024] (prescaled)
    bf16* Ob  = Qb;                       // alias (Qb dead after attn) — bf16 delta
    bf16* Kb  = (bf16*)(ws + 79691776);   //  4 MB  [2048,1024]
    bf16* Vtb = (bf16*)(ws + 83886080);   //  4 MB  [B*H, 512] transposed

    qkv_gemm<<<1280, 256, 0, stream>>>(hs, at, Wq, Wk, Wv,
                                       bq, bk, bv, Qb, Kb, Vtb);

    attn_kernel<<<dim3(32, 16, 4), 256, 0, stream>>>(Qb, Kb, Vtb, maskp, ctx);

    gemm_o<<<dim3(128, 8), 256, 0, stream>>>(ctx, Wo, bo, Ob, rsp);
    ln_kernel<<<16384, 256, 0, stream>>>(Ob, (float*)d_out, gamma, beta);
}

// Round 6
// 327.463 us; speedup vs baseline: 1.1335x; 1.1335x over previous
//
#include <hip/hip_runtime.h>
#include <hip/hip_bf16.h>
#include <cstdint>
#include <cstddef>

// Problem constants
#define B_  4
#define S_  4096
#define A_  512
#define H_  1024
#define NH_ 16
#define HD_ 64

typedef __bf16 bf16;
typedef __bf16 bf16x8 __attribute__((ext_vector_type(8)));
typedef __bf16 bf16x4 __attribute__((ext_vector_type(4)));
typedef float  fx4    __attribute__((ext_vector_type(4)));

typedef __attribute__((address_space(3))) void LDS_v;
typedef const __attribute__((address_space(1))) void GLB_v;

__device__ __forceinline__ void gl_lds16(const void* g, void* l) {
    __builtin_amdgcn_global_load_lds((GLB_v*)g, (LDS_v*)l, 16, 0, 0);
}

__device__ __forceinline__ float sanf(float x) {
    if (x != x) return 0.f;                       // NaN -> 0
    if (fabsf(x) == __builtin_inff()) return x > 0.f ? 10000.f : -10000.f;
    return x;
}

// ---------------------------------------------------------------- fused cast (all 6 inputs, one dispatch)
__global__ __launch_bounds__(256) void cast_all(const float* __restrict__ hs,
                                                const float* __restrict__ at,
                                                const float* __restrict__ wq,
                                                const float* __restrict__ wk,
                                                const float* __restrict__ wv,
                                                const float* __restrict__ wo,
                                                bf16* __restrict__ dhs, bf16* __restrict__ dat,
                                                bf16* __restrict__ dwq, bf16* __restrict__ dwk,
                                                bf16* __restrict__ dwv, bf16* __restrict__ dwo) {
    int i = blockIdx.x * 256 + threadIdx.x;
    const float* s; bf16* d; int off;
    if (i < 4194304)      { s = hs; d = dhs; off = i; }
    else if (i < 4718592) { s = at; d = dat; off = i - 4194304; }
    else if (i < 4980736) { s = wq; d = dwq; off = i - 4718592; }
    else if (i < 5242880) { s = wk; d = dwk; off = i - 4980736; }
    else if (i < 5505024) { s = wv; d = dwv; off = i - 5242880; }
    else                  { s = wo; d = dwo; off = i - 5505024; }
    float4 v = ((const float4*)s)[off];
    bf16x4 o;
    o[0] = (bf16)sanf(v.x); o[1] = (bf16)sanf(v.y);
    o[2] = (bf16)sanf(v.z); o[3] = (bf16)sanf(v.w);
    *(bf16x4*)&d[(size_t)off * 4] = o;
}

// ---------------------------------------------------------------- fused QKV GEMM (one dispatch, 1280 blocks)
// R3 structure — the fastest measured (64.9 us): bf16 inputs via gl_lds16,
// direct scalar epilogue stores for Q/K, packed bf16x4 for V^T.
// id <1024: Q = hsb@wq^T (+bq) * log2e/8 -> Qb bf16
// id <1152: K = atb@wk^T (+bk)           -> Kb bf16
// else    : V = atb@wv^T (+bv)           -> Vtb bf16 transposed [(b*H+n)*512+a]
__global__ __launch_bounds__(256) void qkv_gemm(const bf16* __restrict__ hsb,
                                                const bf16* __restrict__ atb,
                                                const bf16* __restrict__ wqb,
                                                const bf16* __restrict__ wkb,
                                                const bf16* __restrict__ wvb,
                                                const float* __restrict__ bq,
                                                const float* __restrict__ bk,
                                                const float* __restrict__ bv,
                                                bf16* __restrict__ Qb,
                                                bf16* __restrict__ Kb,
                                                bf16* __restrict__ Vtb) {
    __shared__ __align__(16) bf16 As[128 * 32];
    __shared__ __align__(16) bf16 Bs[128 * 32];

    const int id = blockIdx.x;
    int mode, m0, n0;
    const bf16 *A, *Bt; const float* bias;
    if (id < 1024)      { mode = 0; m0 = (id & 127) * 128; n0 = (id >> 7) * 128; A = hsb; Bt = wqb; bias = bq; }
    else if (id < 1152) { int t = id - 1024; mode = 1; m0 = (t & 15) * 128; n0 = (t >> 4) * 128; A = atb; Bt = wkb; bias = bk; }
    else                { int t = id - 1152; mode = 2; m0 = (t & 15) * 128; n0 = (t >> 4) * 128; A = atb; Bt = wvb; bias = bv; }

    const int tid  = threadIdx.x;
    const int lane = tid & 63;
    const int wv   = tid >> 6;
    const int wr   = wv >> 1, wc = wv & 1;
    const int lr   = lane & 15, kq = lane >> 4;

    fx4 acc[4][4] = {};

    const bf16* Ag = A  + (size_t)m0 * 1024;
    const bf16* Bg = Bt + (size_t)n0 * 1024;
    const int c0 = tid, c1 = tid + 256;
    const int row0 = c0 >> 2, kc0 = c0 & 3;
    const int row1 = c1 >> 2, kc1 = c1 & 3;

    for (int k0 = 0; k0 < 1024; k0 += 32) {
        gl_lds16(Ag + (size_t)row0 * 1024 + k0 + kc0 * 8, &As[c0 * 8]);
        gl_lds16(Ag + (size_t)row1 * 1024 + k0 + kc1 * 8, &As[c1 * 8]);
        gl_lds16(Bg + (size_t)row0 * 1024 + k0 + kc0 * 8, &Bs[c0 * 8]);
        gl_lds16(Bg + (size_t)row1 * 1024 + k0 + kc1 * 8, &Bs[c1 * 8]);
        __syncthreads();
        bf16x8 af[4], bfr[4];
#pragma unroll
        for (int i = 0; i < 4; i++) af[i]  = *(const bf16x8*)&As[(wr * 64 + i * 16 + lr) * 32 + kq * 8];
#pragma unroll
        for (int j = 0; j < 4; j++) bfr[j] = *(const bf16x8*)&Bs[(wc * 64 + j * 16 + lr) * 32 + kq * 8];
#pragma unroll
        for (int i = 0; i < 4; i++)
#pragma unroll
            for (int j = 0; j < 4; j++)
                acc[i][j] = __builtin_amdgcn_mfma_f32_16x16x32_bf16(af[i], bfr[j], acc[i][j], 0, 0, 0);
        __syncthreads();
    }

    float bb[4];
#pragma unroll
    for (int j = 0; j < 4; j++) bb[j] = bias[n0 + wc * 64 + j * 16 + lr];

    if (mode == 0) {
        const float sc = 0.18033688011112042f;  // log2(e)/8 prescale for exp2-domain scores
#pragma unroll
        for (int i = 0; i < 4; i++) {
            int row = m0 + wr * 64 + i * 16 + kq * 4;
#pragma unroll
            for (int j = 0; j < 4; j++) {
                int col = n0 + wc * 64 + j * 16 + lr;
#pragma unroll
                for (int r = 0; r < 4; r++)
                    Qb[(size_t)(row + r) * 1024 + col] = (bf16)((acc[i][j][r] + bb[j]) * sc);
            }
        }
    } else if (mode == 1) {
#pragma unroll
        for (int i = 0; i < 4; i++) {
            int row = m0 + wr * 64 + i * 16 + kq * 4;
#pragma unroll
            for (int j = 0; j < 4; j++) {
                int col = n0 + wc * 64 + j * 16 + lr;
#pragma unroll
                for (int r = 0; r < 4; r++)
                    Kb[(size_t)(row + r) * 1024 + col] = (bf16)(acc[i][j][r] + bb[j]);
            }
        }
    } else {
        // V: transposed output, r-contiguous -> packed bf16x4 stores
#pragma unroll
        for (int i = 0; i < 4; i++) {
            int m = m0 + wr * 64 + i * 16 + kq * 4;  // m = b*512 + a
            int bidx = m >> 9, a = m & 511;
#pragma unroll
            for (int j = 0; j < 4; j++) {
                int col = n0 + wc * 64 + j * 16 + lr;
                bf16x4 o;
#pragma unroll
                for (int r = 0; r < 4; r++) o[r] = (bf16)(acc[i][j][r] + bb[j]);
                *(bf16x4*)&Vtb[((size_t)bidx * H_ + col) * A_ + a] = o;
            }
        }
    }
}

// ---------------------------------------------------------------- O-proj GEMM: delta bf16 = (ctx@Wo^T + bo) * rs
// R3 staging (gl_lds16, bf16 weights) + direct scalar bf16 stores (no LDS
// transpose — R4 showed it regresses) + bf16 output (halves write + LN read).
__global__ __launch_bounds__(256) void gemm_o(const bf16* __restrict__ A,
                                              const bf16* __restrict__ Bt,
                                              const float* __restrict__ bias,
                                              bf16* __restrict__ C,
                                              const float* __restrict__ rsp) {
    __shared__ __align__(16) bf16 As[128 * 32];
    __shared__ __align__(16) bf16 Bs[128 * 32];

    const int tid  = threadIdx.x;
    const int lane = tid & 63;
    const int wv   = tid >> 6;
    const int wr   = wv >> 1, wc = wv & 1;
    const int lr   = lane & 15, kq = lane >> 4;
    const int m0   = blockIdx.x * 128, n0 = blockIdx.y * 128;

    fx4 acc[4][4] = {};

    const bf16* Ag = A  + (size_t)m0 * 1024;
    const bf16* Bg = Bt + (size_t)n0 * 1024;
    const int c0 = tid, c1 = tid + 256;
    const int row0 = c0 >> 2, kc0 = c0 & 3;
    const int row1 = c1 >> 2, kc1 = c1 & 3;

    for (int k0 = 0; k0 < 1024; k0 += 32) {
        gl_lds16(Ag + (size_t)row0 * 1024 + k0 + kc0 * 8, &As[c0 * 8]);
        gl_lds16(Ag + (size_t)row1 * 1024 + k0 + kc1 * 8, &As[c1 * 8]);
        gl_lds16(Bg + (size_t)row0 * 1024 + k0 + kc0 * 8, &Bs[c0 * 8]);
        gl_lds16(Bg + (size_t)row1 * 1024 + k0 + kc1 * 8, &Bs[c1 * 8]);
        __syncthreads();
        bf16x8 af[4], bfr[4];
#pragma unroll
        for (int i = 0; i < 4; i++) af[i]  = *(const bf16x8*)&As[(wr * 64 + i * 16 + lr) * 32 + kq * 8];
#pragma unroll
        for (int j = 0; j < 4; j++) bfr[j] = *(const bf16x8*)&Bs[(wc * 64 + j * 16 + lr) * 32 + kq * 8];
#pragma unroll
        for (int i = 0; i < 4; i++)
#pragma unroll
            for (int j = 0; j < 4; j++)
                acc[i][j] = __builtin_amdgcn_mfma_f32_16x16x32_bf16(af[i], bfr[j], acc[i][j], 0, 0, 0);
        __syncthreads();
    }

    float bb[4];
#pragma unroll
    for (int j = 0; j < 4; j++) bb[j] = bias[n0 + wc * 64 + j * 16 + lr];
    float rs = fminf(fmaxf(rsp[0], 0.f), 0.3f);
#pragma unroll
    for (int i = 0; i < 4; i++) {
        int row = m0 + wr * 64 + i * 16 + kq * 4;
#pragma unroll
        for (int j = 0; j < 4; j++) {
            int col = n0 + wc * 64 + j * 16 + lr;
#pragma unroll
            for (int r = 0; r < 4; r++)
                C[(size_t)(row + r) * 1024 + col] = (bf16)(rs * (acc[i][j][r] + bb[j]));
        }
    }
}

// ---------------------------------------------------------------- attention (unchanged — best measured)
// S^T = K·Q^T keeps P in registers (A-operand layout via free k-permutation);
// permuted V^T LDS layout makes every PV B-fragment one conflict-free b128.
__global__ __launch_bounds__(256, 4) void attn_kernel(const bf16* __restrict__ Q,
                                                      const bf16* __restrict__ Kb,
                                                      const bf16* __restrict__ Vt,
                                                      const int* __restrict__ mask,
                                                      bf16* __restrict__ ctx) {
    __shared__ __align__(16) bf16 Qs[128 * 72];   // padded; reused for ctx staging
    __shared__ __align__(16) bf16 Ks[64 * 72];    // K [a][d], padded
    __shared__ __align__(16) bf16 Vts[64 * 72];   // V^T [d][a-permuted], padded
    __shared__ float smask[512];                  // caps: +/- 50*log2e
    __shared__ float dnm[128];

    const int tid  = threadIdx.x;
    const int lane = tid & 63;
    const int wv   = tid >> 6;
    const int lr   = lane & 15, kq = lane >> 4;
    const int st = blockIdx.x, h = blockIdx.y, b = blockIdx.z;
    const int m0 = b * S_ + st * 128;
    const float LO = -72.134752f;                 // -50*log2e

    // --- stage Q (padded, via VGPRs) + mask caps
    bf16x8 qtmp[4];
#pragma unroll
    for (int i = 0; i < 4; i++) {
        int c = tid + i * 256, row = c >> 3, ch = c & 7;
        qtmp[i] = *(const bf16x8*)(Q + (size_t)(m0 + row) * H_ + h * 64 + ch * 8);
    }
    smask[tid]       = (mask[b * A_ + tid] > 0)       ? -LO : LO;
    smask[tid + 256] = (mask[b * A_ + tid + 256] > 0) ? -LO : LO;
#pragma unroll
    for (int i = 0; i < 4; i++) {
        int c = tid + i * 256, row = c >> 3, ch = c & 7;
        *(bf16x8*)&Qs[row * 72 + ch * 8] = qtmp[i];
    }

    // staging coords
    const int srow = tid >> 2, sseg = tid & 3;
    const size_t kg = (size_t)(b * A_ + srow) * H_ + h * 64 + sseg * 16;
    const bf16* vrow = Vt + (size_t)(b * H_ + h * 64 + srow) * A_;
    const int va0 = 32 * (sseg >> 1) + 4 * ((2 * sseg) & 3);      // u=0 source base
    const int va1 = 32 * (sseg >> 1) + 4 * ((2 * sseg + 1) & 3);  // u=1 source base

    // prefetch tile 0
    bf16x8 kr0 = *(const bf16x8*)(Kb + kg);
    bf16x8 kr1 = *(const bf16x8*)(Kb + kg + 8);
    bf16x4 v00 = *(const bf16x4*)(vrow + va0);
    bf16x4 v01 = *(const bf16x4*)(vrow + va0 + 16);
    bf16x4 v10 = *(const bf16x4*)(vrow + va1);
    bf16x4 v11 = *(const bf16x4*)(vrow + va1 + 16);

    fx4 acco[2][4] = {};          // [st][dt] : ctx[s=wv*32+st*16+kq*4+r][d=dt*16+lr]
    float dloc[2] = {0.f, 0.f};   // per-lane partial denominators per s-16-block

    for (int it = 0; it < 8; it++) {
        const int a0 = it * 64;
        __syncthreads();  // prev compute done reading Ks/Vts (it=0: Q/mask writes ordered)
        *(bf16x8*)&Ks[srow * 72 + sseg * 16]      = kr0;
        *(bf16x8*)&Ks[srow * 72 + sseg * 16 + 8]  = kr1;
        *(bf16x8*)&Vts[srow * 72 + sseg * 16] =
            __builtin_shufflevector(v00, v01, 0, 1, 2, 3, 4, 5, 6, 7);
        *(bf16x8*)&Vts[srow * 72 + sseg * 16 + 8] =
            __builtin_shufflevector(v10, v11, 0, 1, 2, 3, 4, 5, 6, 7);
        __syncthreads();  // staging visible (lgkm only — no LDS-writing vmem in flight)

        if (it < 7) {     // register prefetch for it+1 (uniform branch)
            const size_t ko = kg + (size_t)(a0 + 64) * H_;
            kr0 = *(const bf16x8*)(Kb + ko);
            kr1 = *(const bf16x8*)(Kb + ko + 8);
            v00 = *(const bf16x4*)(vrow + a0 + 64 + va0);
            v01 = *(const bf16x4*)(vrow + a0 + 64 + va0 + 16);
            v10 = *(const bf16x4*)(vrow + a0 + 64 + va1);
            v11 = *(const bf16x4*)(vrow + a0 + 64 + va1 + 16);
        }

        // ---- S^T = K·Q^T  (M=a 64, N=s; wave owns s in [wv*32, wv*32+32))
        fx4 accs[4][2] = {};   // [mt][nt] : S^T[a=mt*16+kq*4+r][s=wv*32+nt*16+lr]
#pragma unroll
        for (int kk = 0; kk < 64; kk += 32) {
            bf16x8 kf[4], qf[2];
#pragma unroll
            for (int mt = 0; mt < 4; mt++)
                kf[mt] = *(const bf16x8*)&Ks[(mt * 16 + lr) * 72 + kk + kq * 8];
#pragma unroll
            for (int nt = 0; nt < 2; nt++)
                qf[nt] = *(const bf16x8*)&Qs[(wv * 32 + nt * 16 + lr) * 72 + kk + kq * 8];
#pragma unroll
            for (int mt = 0; mt < 4; mt++)
#pragma unroll
                for (int nt = 0; nt < 2; nt++)
                    accs[mt][nt] = __builtin_amdgcn_mfma_f32_16x16x32_bf16(kf[mt], qf[nt], accs[mt][nt], 0, 0, 0);
        }

        // ---- softmax numerator in-register: P fragments (bf16) + denom partials
        bf16x4 pf[4][2];
#pragma unroll
        for (int mt = 0; mt < 4; mt++) {
            fx4 cap = *(const fx4*)&smask[a0 + mt * 16 + kq * 4];
#pragma unroll
            for (int nt = 0; nt < 2; nt++) {
#pragma unroll
                for (int r = 0; r < 4; r++) {
                    float s2 = fmaxf(fminf(accs[mt][nt][r], cap[r]), LO);
                    float p  = __builtin_amdgcn_exp2f(s2);
                    pf[mt][nt][r] = (bf16)p;
                    dloc[nt] += p;
                }
            }
        }

        // ---- PV: ctx += P·V. A = P from regs (permuted k-order), B = V^T LDS (b128).
#pragma unroll
        for (int ks = 0; ks < 2; ks++) {
            bf16x8 pa[2];
#pragma unroll
            for (int stl = 0; stl < 2; stl++)
                pa[stl] = __builtin_shufflevector(pf[2 * ks][stl], pf[2 * ks + 1][stl],
                                                  0, 1, 2, 3, 4, 5, 6, 7);
#pragma unroll
            for (int dt = 0; dt < 4; dt++) {
                bf16x8 vf = *(const bf16x8*)&Vts[(dt * 16 + lr) * 72 + ks * 32 + kq * 8];
#pragma unroll
                for (int stl = 0; stl < 2; stl++)
                    acco[stl][dt] = __builtin_amdgcn_mfma_f32_16x16x32_bf16(pa[stl], vf, acco[stl][dt], 0, 0, 0);
            }
        }
    }

    // ---- denominators: reduce across quads, publish per s-row
#pragma unroll
    for (int nt = 0; nt < 2; nt++) {
        dloc[nt] += __shfl_xor(dloc[nt], 16);
        dloc[nt] += __shfl_xor(dloc[nt], 32);
    }
    if (kq == 0) {
        dnm[wv * 32 + lr]      = dloc[0];
        dnm[wv * 32 + 16 + lr] = dloc[1];
    }
    __syncthreads();  // dnm visible; Qs free (last read in final QK^T)

    // ---- normalize + stage ctx tile into Qs (padded), then vectorized store
#pragma unroll
    for (int stl = 0; stl < 2; stl++) {
        fx4 dv = *(const fx4*)&dnm[wv * 32 + stl * 16 + kq * 4];
        float ri[4];
#pragma unroll
        for (int r = 0; r < 4; r++) ri[r] = __builtin_amdgcn_rcpf(dv[r]);
#pragma unroll
        for (int dt = 0; dt < 4; dt++)
#pragma unroll
            for (int r = 0; r < 4; r++)
                Qs[(wv * 32 + stl * 16 + kq * 4 + r) * 72 + dt * 16 + lr] =
                    (bf16)(acco[stl][dt][r] * ri[r]);
    }
    __syncthreads();
#pragma unroll
    for (int i = 0; i < 4; i++) {
        int c = tid + i * 256, row = c >> 3, ch = c & 7;
        *(bf16x8*)&ctx[(size_t)(m0 + row) * H_ + h * 64 + ch * 8] = *(const bf16x8*)&Qs[row * 72 + ch * 8];
    }
}

// ---------------------------------------------------------------- LayerNorm: bf16 delta -> fp32 out
__global__ __launch_bounds__(256) void ln_kernel(const bf16* __restrict__ in,
                                                 float* __restrict__ out,
                                                 const float* __restrict__ gamma,
                                                 const float* __restrict__ beta) {
    __shared__ float red[8];
    const int tid = threadIdx.x;
    bf16x4 xb = *(const bf16x4*)&in[(size_t)blockIdx.x * 1024 + tid * 4];
    float x0 = (float)xb[0], x1 = (float)xb[1], x2 = (float)xb[2], x3 = (float)xb[3];
    float s = x0 + x1 + x2 + x3;
    float q = x0 * x0 + x1 * x1 + x2 * x2 + x3 * x3;
#pragma unroll
    for (int off = 32; off > 0; off >>= 1) {
        s += __shfl_down(s, off);
        q += __shfl_down(q, off);
    }
    if ((tid & 63) == 0) { red[(tid >> 6) * 2] = s; red[(tid >> 6) * 2 + 1] = q; }
    __syncthreads();
    s = red[0] + red[2] + red[4] + red[6];
    q = red[1] + red[3] + red[5] + red[7];
    float mean = s * (1.f / 1024.f);
    float var  = q * (1.f / 1024.f) - mean * mean;
    float inv  = rsqrtf(var + 1e-5f);
    float4 g  = ((const float4*)gamma)[tid];
    float4 bb = ((const float4*)beta)[tid];
    float4 y;
    y.x = (x0 - mean) * inv * g.x + bb.x;
    y.y = (x1 - mean) * inv * g.y + bb.y;
    y.z = (x2 - mean) * inv * g.z + bb.z;
    y.w = (x3 - mean) * inv * g.w + bb.w;
    ((float4*)(out + (size_t)blockIdx.x * 1024))[tid] = y;
}

// ---------------------------------------------------------------- launch
extern "C" void kernel_launch(void* const* d_in, const int* in_sizes, int n_in,
                              void* d_out, int out_size, void* d_ws, size_t ws_size,
                              hipStream_t stream) {
    const float* hs    = (const float*)d_in[0];
    const float* at    = (const float*)d_in[1];
    const int*   maskp = (const int*)d_in[2];
    const float* Wq    = (const float*)d_in[3];
    const float* bq    = (const float*)d_in[4];
    const float* Wk    = (const float*)d_in[5];
    const float* bk    = (const float*)d_in[6];
    const float* Wv    = (const float*)d_in[7];
    const float* bv    = (const float*)d_in[8];
    const float* Wo    = (const float*)d_in[9];
    const float* bo    = (const float*)d_in[10];
    const float* gamma = (const float*)d_in[11];
    const float* beta  = (const float*)d_in[12];
    const float* rsp   = (const float*)d_in[13];

    char* ws = (char*)d_ws;
    bf16* hsb = (bf16*)(ws + 0);          // 32 MB  [16384,1024]
    bf16* ctx = (bf16*)(ws + 0);          // alias (hs dead after qkv_gemm)
    bf16* atb = (bf16*)(ws + 33554432);   //  4 MB  [2048,1024]
    bf16* wqb = (bf16*)(ws + 37748736);   //  2 MB
    bf16* wkb = (bf16*)(ws + 39845888);   //  2 MB
    bf16* wvb = (bf16*)(ws + 41943040);   //  2 MB
    bf16* wob = (bf16*)(ws + 44040192);   //  2 MB
    bf16* Qb  = (bf16*)(ws + 46137344);   // 32 MB  [16384,1024] (prescaled)
    bf16* Ob  = Qb;                       // alias (Qb dead after attn) — bf16 delta
    bf16* Kb  = (bf16*)(ws + 79691776);   //  4 MB  [2048,1024]
    bf16* Vtb = (bf16*)(ws + 83886080);   //  4 MB  [B*H, 512] transposed

    cast_all<<<22528, 256, 0, stream>>>(hs, at, Wq, Wk, Wv, Wo,
                                        hsb, atb, wqb, wkb, wvb, wob);

    qkv_gemm<<<1280, 256, 0, stream>>>(hsb, atb, wqb, wkb, wvb,
                                       bq, bk, bv, Qb, Kb, Vtb);

    attn_kernel<<<dim3(32, 16, 4), 256, 0, stream>>>(Qb, Kb, Vtb, maskp, ctx);

    gemm_o<<<dim3(128, 8), 256, 0, stream>>>(ctx, wob, bo, Ob, rsp);
    ln_kernel<<<16384, 256, 0, stream>>>(Ob, (float*)d_out, gamma, beta);
}